// Round 2
// 1285.887 us; speedup vs baseline: 1.2992x; 1.2992x over previous
//
#include <hip/hip_runtime.h>
#include <stdint.h>
#include <stddef.h>

#define T_TOK 4096
#define H_DIM 1024
#define E_NUM 8
#define F_DIM 4096
#define KSPLIT 4

typedef unsigned short u16;
typedef __attribute__((ext_vector_type(4))) float floatx4;
typedef __attribute__((ext_vector_type(8))) __bf16 bf16x8;
typedef __attribute__((ext_vector_type(8))) u16 u16x8;
typedef __attribute__((ext_vector_type(4))) u16 u16x4;

__device__ __forceinline__ u16 f2bf(float f) {
    union { float f; unsigned int i; } v; v.f = f;
    unsigned int r = v.i + 0x7FFFu + ((v.i >> 16) & 1u);  // round-to-nearest-even
    return (u16)(r >> 16);
}
__device__ __forceinline__ float gelu_tanh(float v) {
    float u = 0.7978845608028654f * (v + 0.044715f * v * v * v);
    u = fminf(fmaxf(u, -15.f), 15.f);
    float e = __expf(2.f * u);
    return 0.5f * v * (1.f + (e - 1.f) / (e + 1.f));
}

// async global->LDS, 16B per lane; lds base must be wave-uniform (HW adds lane*16)
#define GLOAD_LDS16(g, l)                                                              \
    __builtin_amdgcn_global_load_lds((const __attribute__((address_space(1))) void*)(g), \
                                     (__attribute__((address_space(3))) void*)(l), 16, 0, 0)

// ---------------- fp32 -> bf16 convert (n multiple of 1024) ----------------
__global__ __launch_bounds__(256) void convert_bf16_kernel(const float* __restrict__ src,
                                                           u16* __restrict__ dst, int n) {
    int i = (blockIdx.x * 256 + threadIdx.x) * 4;
    if (i >= n) return;
    floatx4 v = *(const floatx4*)(src + i);
    u16x4 o;
#pragma unroll
    for (int j = 0; j < 4; ++j) o[j] = f2bf(v[j]);
    *(u16x4*)(dst + i) = o;
}

// ---------------- router: softmax -> top-2 -> dense cw[T,E] + per-expert token lists ----------------
__global__ __launch_bounds__(256) void router_kernel(const float* __restrict__ x,
                                                     const float* __restrict__ rw,
                                                     float* __restrict__ cw,
                                                     int* __restrict__ cnt,
                                                     int* __restrict__ lists) {
    int tok = blockIdx.x * 4 + (threadIdx.x >> 6);
    int lane = threadIdx.x & 63;
    const floatx4* xp = (const floatx4*)(x + (size_t)tok * H_DIM + lane * 16);
    floatx4 xv[4];
#pragma unroll
    for (int q = 0; q < 4; ++q) xv[q] = xp[q];
    float logits[E_NUM];
#pragma unroll
    for (int e = 0; e < E_NUM; ++e) {
        const floatx4* wp = (const floatx4*)(rw + (size_t)e * H_DIM + lane * 16);
        float s = 0.f;
#pragma unroll
        for (int q = 0; q < 4; ++q) {
            floatx4 wv = wp[q];
#pragma unroll
            for (int j = 0; j < 4; ++j) s += xv[q][j] * wv[j];
        }
#pragma unroll
        for (int off = 32; off > 0; off >>= 1) s += __shfl_xor(s, off, 64);
        logits[e] = s;
    }
    float m = logits[0];
#pragma unroll
    for (int e = 1; e < E_NUM; ++e) m = fmaxf(m, logits[e]);
    float p[E_NUM];
    float sum = 0.f;
#pragma unroll
    for (int e = 0; e < E_NUM; ++e) { p[e] = __expf(logits[e] - m); sum += p[e]; }
    float inv = 1.f / sum;
    int i1 = 0;
#pragma unroll
    for (int e = 1; e < E_NUM; ++e) if (logits[e] > logits[i1]) i1 = e;
    int i2 = (i1 == 0) ? 1 : 0;
#pragma unroll
    for (int e = 0; e < E_NUM; ++e) if (e != i1 && logits[e] > logits[i2]) i2 = e;
    if (lane == 0) {
        int p1 = atomicAdd(&cnt[i1], 1);
        lists[i1 * T_TOK + p1] = tok;
        int p2 = atomicAdd(&cnt[i2], 1);
        lists[i2 * T_TOK + p2] = tok;
    }
    if (lane < E_NUM) {
        float v = (lane == i1) ? p[i1] * inv : ((lane == i2) ? p[i2] * inv : 0.f);
        cw[tok * E_NUM + lane] = v;
    }
}

// ---------------- w2[e] [F,H] fp32 -> w2t [H,F] bf16 ----------------
__global__ __launch_bounds__(256) void transpose_convert_w2(const float* __restrict__ w2e,
                                                            u16* __restrict__ w2t) {
    __shared__ u16 t[32][36];
    const int f0 = blockIdx.x * 32;
    const int h0 = blockIdx.y * 32;
    const int r = threadIdx.x >> 3;         // 0..31
    const int c4 = (threadIdx.x & 7) * 4;   // 0..28
    floatx4 v = *(const floatx4*)(w2e + (size_t)(f0 + r) * H_DIM + h0 + c4);
#pragma unroll
    for (int j = 0; j < 4; ++j) t[r][c4 + j] = f2bf(v[j]);
    __syncthreads();
    u16x4 o;
#pragma unroll
    for (int j = 0; j < 4; ++j) o[j] = t[c4 + j][r];
    *(u16x4*)(w2t + (size_t)(h0 + r) * F_DIM + f0 + c4) = o;
}

__global__ __launch_bounds__(256) void zero_f32_kernel(float* __restrict__ p) {
    int i = blockIdx.x * 256 + threadIdx.x;
    floatx4 z = {0.f, 0.f, 0.f, 0.f};
    ((floatx4*)p)[i] = z;
}

// ---------------- GEMM1 (sparse, gathered A): h12[slot] = gelu(x[tok] @ w1e^T) * (x[tok] @ v1e^T) ----------------
// xb [T,H] bf16 row-major (gathered via lists), w1b/v1b [F,H] bf16 row-major (NT).
// Tile 128x128, BK=32, 4 waves. m-blocks past cnt[e] early-exit.
__global__ __launch_bounds__(256, 2) void gemm1_kernel(const u16* __restrict__ x,
                                                       const u16* __restrict__ w1e,
                                                       const u16* __restrict__ v1e,
                                                       u16* __restrict__ h12,
                                                       const int* __restrict__ cnt,
                                                       const int* __restrict__ lists,
                                                       int e) {
    const int cnt_e = cnt[e];
    const int m0 = blockIdx.y * 128;  // slot base within expert
    if (m0 >= cnt_e) return;
    __shared__ __align__(16) u16 lA[128 * 32];
    __shared__ __align__(16) u16 lB1[128 * 32];
    __shared__ __align__(16) u16 lB2[128 * 32];
    const int n0 = blockIdx.x * 128;  // f
    const int w = threadIdx.x >> 6;
    const int lane = threadIdx.x & 63;
    const int wm = w >> 1, wn = w & 1;
    const int srow = lane >> 2;
    const int scol = (lane & 3) * 8;
    const int lrow = lane & 15;
    const int lkq = (lane >> 4) * 8;

    // gather: per-lane A-row base pointers (token indices, hoisted out of K-loop)
    const int* le = lists + e * T_TOK;
    const u16* gA[2];
#pragma unroll
    for (int r = 0; r < 2; ++r) {
        int seg = w * 2 + r;
        int row = seg * 16 + srow;
        gA[r] = x + (size_t)le[m0 + row] * H_DIM + scol;
    }

    floatx4 acc1[4][4], acc2[4][4];
    floatx4 z = {0.f, 0.f, 0.f, 0.f};
#pragma unroll
    for (int mt = 0; mt < 4; ++mt)
#pragma unroll
        for (int nt = 0; nt < 4; ++nt) { acc1[mt][nt] = z; acc2[mt][nt] = z; }

    for (int k0 = 0; k0 < H_DIM; k0 += 32) {
#pragma unroll
        for (int r = 0; r < 2; ++r) {
            int seg = w * 2 + r;             // 0..7, 16 rows each
            int row = seg * 16 + srow;
            GLOAD_LDS16(gA[r] + k0, lA + seg * 512);
            GLOAD_LDS16(w1e + (size_t)(n0 + row) * H_DIM + k0 + scol, lB1 + seg * 512);
            GLOAD_LDS16(v1e + (size_t)(n0 + row) * H_DIM + k0 + scol, lB2 + seg * 512);
        }
        __syncthreads();
        bf16x8 a[4], b1[4], b2[4];
#pragma unroll
        for (int mt = 0; mt < 4; ++mt)
            a[mt] = *(const bf16x8*)(lA + (wm * 64 + mt * 16 + lrow) * 32 + lkq);
#pragma unroll
        for (int nt = 0; nt < 4; ++nt) {
            b1[nt] = *(const bf16x8*)(lB1 + (wn * 64 + nt * 16 + lrow) * 32 + lkq);
            b2[nt] = *(const bf16x8*)(lB2 + (wn * 64 + nt * 16 + lrow) * 32 + lkq);
        }
#pragma unroll
        for (int mt = 0; mt < 4; ++mt)
#pragma unroll
            for (int nt = 0; nt < 4; ++nt) {
                acc1[mt][nt] = __builtin_amdgcn_mfma_f32_16x16x32_bf16(a[mt], b1[nt], acc1[mt][nt], 0, 0, 0);
                acc2[mt][nt] = __builtin_amdgcn_mfma_f32_16x16x32_bf16(a[mt], b2[nt], acc2[mt][nt], 0, 0, 0);
            }
        __syncthreads();
    }
    const int orow = (lane >> 4) * 4;
    const int ocol = lane & 15;
#pragma unroll
    for (int mt = 0; mt < 4; ++mt) {
#pragma unroll
        for (int i = 0; i < 4; ++i) {
            int row = m0 + wm * 64 + mt * 16 + orow + i;   // compacted slot (garbage past cnt_e is fine)
            u16* dst = h12 + (size_t)row * F_DIM + n0 + wn * 64;
#pragma unroll
            for (int nt = 0; nt < 4; ++nt) {
                dst[nt * 16 + ocol] = f2bf(gelu_tanh(acc1[mt][nt][i]) * acc2[mt][nt][i]);
            }
        }
    }
}

// ---------------- GEMM2 (sparse, split-K=4): out[tok] += (h12[slot] @ w2t^T) * cw[tok,e] ----------------
// h12 compacted [slot,F] bf16, w2te [H,F] bf16. Scatter-accumulate via fp32 HW atomics.
__global__ __launch_bounds__(256, 2) void gemm2_kernel(const u16* __restrict__ h12,
                                                       const u16* __restrict__ w2te,
                                                       const float* __restrict__ cw,
                                                       float* __restrict__ out_f32,
                                                       const int* __restrict__ cnt,
                                                       const int* __restrict__ lists,
                                                       int e) {
    const int cnt_e = cnt[e];
    const int m0 = blockIdx.y * 128;  // slot base
    if (m0 >= cnt_e) return;
    __shared__ __align__(16) u16 lA[128 * 32];
    __shared__ __align__(16) u16 lB[128 * 32];
    const int n0 = blockIdx.x * 128;                 // h
    const int kz = blockIdx.z * (F_DIM / KSPLIT);    // K-slice base
    const int w = threadIdx.x >> 6;
    const int lane = threadIdx.x & 63;
    const int wm = w >> 1, wn = w & 1;
    const int srow = lane >> 2;
    const int scol = (lane & 3) * 8;
    const int lrow = lane & 15;
    const int lkq = (lane >> 4) * 8;

    floatx4 acc[4][4];
    floatx4 z = {0.f, 0.f, 0.f, 0.f};
#pragma unroll
    for (int mt = 0; mt < 4; ++mt)
#pragma unroll
        for (int nt = 0; nt < 4; ++nt) acc[mt][nt] = z;

    for (int k0 = kz; k0 < kz + F_DIM / KSPLIT; k0 += 32) {
#pragma unroll
        for (int r = 0; r < 2; ++r) {
            int seg = w * 2 + r;
            int row = seg * 16 + srow;
            GLOAD_LDS16(h12 + (size_t)(m0 + row) * F_DIM + k0 + scol, lA + seg * 512);
            GLOAD_LDS16(w2te + (size_t)(n0 + row) * F_DIM + k0 + scol, lB + seg * 512);
        }
        __syncthreads();
        bf16x8 a[4], b[4];
#pragma unroll
        for (int mt = 0; mt < 4; ++mt)
            a[mt] = *(const bf16x8*)(lA + (wm * 64 + mt * 16 + lrow) * 32 + lkq);
#pragma unroll
        for (int nt = 0; nt < 4; ++nt)
            b[nt] = *(const bf16x8*)(lB + (wn * 64 + nt * 16 + lrow) * 32 + lkq);
#pragma unroll
        for (int mt = 0; mt < 4; ++mt)
#pragma unroll
            for (int nt = 0; nt < 4; ++nt)
                acc[mt][nt] = __builtin_amdgcn_mfma_f32_16x16x32_bf16(a[mt], b[nt], acc[mt][nt], 0, 0, 0);
        __syncthreads();
    }
    const int orow = (lane >> 4) * 4;
    const int ocol = lane & 15;
    const int* le = lists + e * T_TOK;
#pragma unroll
    for (int mt = 0; mt < 4; ++mt) {
#pragma unroll
        for (int i = 0; i < 4; ++i) {
            int slot = m0 + wm * 64 + mt * 16 + orow + i;
            if (slot >= cnt_e) continue;
            int tok = le[slot];
            float cwv = cw[tok * E_NUM + e];
            float* dst = out_f32 + (size_t)tok * H_DIM + n0 + wn * 64;
#pragma unroll
            for (int nt = 0; nt < 4; ++nt) {
                unsafeAtomicAdd(&dst[nt * 16 + ocol], acc[mt][nt][i] * cwv);
            }
        }
    }
}

extern "C" void kernel_launch(void* const* d_in, const int* in_sizes, int n_in,
                              void* d_out, int out_size, void* d_ws, size_t ws_size,
                              hipStream_t stream) {
    const float* x = (const float*)d_in[0];
    const float* rw = (const float*)d_in[1];
    const float* w1 = (const float*)d_in[2];
    const float* v1 = (const float*)d_in[3];
    const float* w2 = (const float*)d_in[4];
    float* out = (float*)d_out;

    char* ws = (char*)d_ws;
    float* cw = (float*)ws;                                   // 128 KB @ 0
    int* lists = (int*)(ws + 0x20000);                        // 128 KB @ 128 KB
    int* cnt = (int*)(ws + 0x40000);                          //  32 B  @ 256 KB
    u16* h12 = (u16*)(ws + (1 << 20));                        // 32 MB  @ 1 MB
    u16* xb = (u16*)(ws + (33u << 20));                       //  8 MB  @ 33 MB
    u16* w1b = (u16*)(ws + (41u << 20));                      //  8 MB  @ 41 MB
    u16* v1b = (u16*)(ws + (49u << 20));                      //  8 MB  @ 49 MB
    u16* w2tb = (u16*)(ws + (57u << 20));                     //  8 MB  @ 57 MB -> 65 MB total

    const int n_x = T_TOK * H_DIM;        // 4 M
    const int n_w = F_DIM * H_DIM;        // 4 M per expert

    // zero cw + lists + cnt (65 blocks * 4096 B = 266240 B = 0x41000, covers cnt)
    zero_f32_kernel<<<65, 256, 0, stream>>>((float*)ws);
    router_kernel<<<T_TOK / 4, 256, 0, stream>>>(x, rw, cw, cnt, lists);
    zero_f32_kernel<<<(T_TOK * H_DIM / 4) / 256, 256, 0, stream>>>(out);
    convert_bf16_kernel<<<(n_x / 4) / 256, 256, 0, stream>>>(x, xb, n_x);

    for (int e = 0; e < E_NUM; ++e) {
        const float* w1e = w1 + (size_t)e * n_w;
        const float* v1e = v1 + (size_t)e * n_w;
        const float* w2e = w2 + (size_t)e * n_w;
        convert_bf16_kernel<<<(n_w / 4) / 256, 256, 0, stream>>>(w1e, w1b, n_w);
        convert_bf16_kernel<<<(n_w / 4) / 256, 256, 0, stream>>>(v1e, v1b, n_w);
        transpose_convert_w2<<<dim3(F_DIM / 32, H_DIM / 32), 256, 0, stream>>>(w2e, w2tb);
        gemm1_kernel<<<dim3(F_DIM / 128, T_TOK / 128), 256, 0, stream>>>(xb, w1b, v1b, h12, cnt, lists, e);
        gemm2_kernel<<<dim3(H_DIM / 128, T_TOK / 128, KSPLIT), 256, 0, stream>>>(h12, w2tb, cw, out, cnt, lists, e);
    }
}

// Round 4
// 797.093 us; speedup vs baseline: 2.0958x; 1.6132x over previous
//
#include <hip/hip_runtime.h>
#include <stdint.h>
#include <stddef.h>

#define T_TOK 4096
#define H_DIM 1024
#define E_NUM 8
#define F_DIM 4096
#define KSPLIT 4        // small-path gemm2 split-K
#define KSPLIT2 2       // big-path gemm2 split-K
#define FH (F_DIM * H_DIM)

typedef unsigned short u16;
typedef __attribute__((ext_vector_type(4))) float floatx4;
typedef __attribute__((ext_vector_type(8))) __bf16 bf16x8;
typedef __attribute__((ext_vector_type(8))) u16 u16x8;
typedef __attribute__((ext_vector_type(4))) u16 u16x4;

__device__ __forceinline__ u16 f2bf(float f) {
    union { float f; unsigned int i; } v; v.f = f;
    unsigned int r = v.i + 0x7FFFu + ((v.i >> 16) & 1u);  // round-to-nearest-even
    return (u16)(r >> 16);
}
__device__ __forceinline__ float gelu_tanh(float v) {
    float u = 0.7978845608028654f * (v + 0.044715f * v * v * v);
    u = fminf(fmaxf(u, -15.f), 15.f);
    float e = __expf(2.f * u);
    return 0.5f * v * (1.f + (e - 1.f) / (e + 1.f));
}

// async global->LDS, 16B per lane; lds base must be wave-uniform (HW adds lane*16)
#define GLOAD_LDS16(g, l)                                                              \
    __builtin_amdgcn_global_load_lds((const __attribute__((address_space(1))) void*)(g), \
                                     (__attribute__((address_space(3))) void*)(l), 16, 0, 0)

// ---------------- fp32 -> bf16 convert (n multiple of 1024) ----------------
__global__ __launch_bounds__(256) void convert_bf16_kernel(const float* __restrict__ src,
                                                           u16* __restrict__ dst, int n) {
    int i = (blockIdx.x * 256 + threadIdx.x) * 4;
    if (i >= n) return;
    floatx4 v = *(const floatx4*)(src + i);
    u16x4 o;
#pragma unroll
    for (int j = 0; j < 4; ++j) o[j] = f2bf(v[j]);
    *(u16x4*)(dst + i) = o;
}

// two-array convert in one dispatch (each array n elems, n multiple of 1024)
__global__ __launch_bounds__(256) void convert2_bf16_kernel(const float* __restrict__ a,
                                                            u16* __restrict__ da,
                                                            const float* __restrict__ b,
                                                            u16* __restrict__ db, int n) {
    int i = (blockIdx.x * 256 + threadIdx.x) * 4;
    const float* s = a;
    u16* d = da;
    if (i >= n) { i -= n; s = b; d = db; }
    floatx4 v = *(const floatx4*)(s + i);
    u16x4 o;
#pragma unroll
    for (int j = 0; j < 4; ++j) o[j] = f2bf(v[j]);
    *(u16x4*)(d + i) = o;
}

// ---------------- router phase A: softmax -> top-2 -> dense cw[T,E] + packed top2 ----------------
__global__ __launch_bounds__(256) void router_kernel(const float* __restrict__ x,
                                                     const float* __restrict__ rw,
                                                     float* __restrict__ cw,
                                                     int* __restrict__ top2) {
    int tok = blockIdx.x * 4 + (threadIdx.x >> 6);
    int lane = threadIdx.x & 63;
    const floatx4* xp = (const floatx4*)(x + (size_t)tok * H_DIM + lane * 16);
    floatx4 xv[4];
#pragma unroll
    for (int q = 0; q < 4; ++q) xv[q] = xp[q];
    float logits[E_NUM];
#pragma unroll
    for (int e = 0; e < E_NUM; ++e) {
        const floatx4* wp = (const floatx4*)(rw + (size_t)e * H_DIM + lane * 16);
        float s = 0.f;
#pragma unroll
        for (int q = 0; q < 4; ++q) {
            floatx4 wv = wp[q];
#pragma unroll
            for (int j = 0; j < 4; ++j) s += xv[q][j] * wv[j];
        }
#pragma unroll
        for (int off = 32; off > 0; off >>= 1) s += __shfl_xor(s, off, 64);
        logits[e] = s;
    }
    float m = logits[0];
#pragma unroll
    for (int e = 1; e < E_NUM; ++e) m = fmaxf(m, logits[e]);
    float p[E_NUM];
    float sum = 0.f;
#pragma unroll
    for (int e = 0; e < E_NUM; ++e) { p[e] = __expf(logits[e] - m); sum += p[e]; }
    float inv = 1.f / sum;
    int i1 = 0;
#pragma unroll
    for (int e = 1; e < E_NUM; ++e) if (logits[e] > logits[i1]) i1 = e;
    int i2 = (i1 == 0) ? 1 : 0;
#pragma unroll
    for (int e = 0; e < E_NUM; ++e) if (e != i1 && logits[e] > logits[i2]) i2 = e;
    if (lane == 0) top2[tok] = i1 | (i2 << 4);
    if (lane < E_NUM) {
        float v = (lane == i1) ? p[i1] * inv : ((lane == i2) ? p[i2] * inv : 0.f);
        cw[tok * E_NUM + lane] = v;
    }
}

// ---------------- router phase B: per-expert compaction (no global atomics) ----------------
// 8 blocks (one per expert) x 256 threads; ballot+popcount prefix sums, deterministic order.
__global__ __launch_bounds__(256) void build_lists_kernel(const int* __restrict__ top2,
                                                          int* __restrict__ cnt,
                                                          int* __restrict__ lists) {
    const int e = blockIdx.x;
    const int w = threadIdx.x >> 6;
    const int lane = threadIdx.x & 63;
    __shared__ int wsum[4];
    __shared__ int srun;
    if (threadIdx.x == 0) srun = 0;
    __syncthreads();
    for (int base = 0; base < T_TOK; base += 256) {
        int tok = base + threadIdx.x;
        int c = top2[tok];
        bool flag = ((c & 15) == e) || (((c >> 4) & 15) == e);
        unsigned long long mask = __ballot(flag);
        int mypre = __popcll(mask & ((1ull << lane) - 1ull));
        if (lane == 0) wsum[w] = __popcll(mask);
        __syncthreads();
        int wpre = 0;
        for (int i = 0; i < w; ++i) wpre += wsum[i];
        int run = srun;
        if (flag) lists[e * T_TOK + run + wpre + mypre] = tok;
        __syncthreads();
        if (threadIdx.x == 0) srun = run + wsum[0] + wsum[1] + wsum[2] + wsum[3];
        __syncthreads();
    }
    if (threadIdx.x == 0) cnt[e] = srun;
}

// ---------------- w2 [F,H] fp32 -> w2t [H,F] bf16 (grid.z = expert) ----------------
__global__ __launch_bounds__(256) void transpose_convert_w2(const float* __restrict__ w2,
                                                            u16* __restrict__ w2t) {
    __shared__ u16 t[32][36];
    const float* w2e = w2 + (size_t)blockIdx.z * FH;
    u16* dst = w2t + (size_t)blockIdx.z * FH;
    const int f0 = blockIdx.x * 32;
    const int h0 = blockIdx.y * 32;
    const int r = threadIdx.x >> 3;         // 0..31
    const int c4 = (threadIdx.x & 7) * 4;   // 0..28
    floatx4 v = *(const floatx4*)(w2e + (size_t)(f0 + r) * H_DIM + h0 + c4);
#pragma unroll
    for (int j = 0; j < 4; ++j) t[r][c4 + j] = f2bf(v[j]);
    __syncthreads();
    u16x4 o;
#pragma unroll
    for (int j = 0; j < 4; ++j) o[j] = t[c4 + j][r];
    *(u16x4*)(dst + (size_t)(h0 + r) * F_DIM + f0 + c4) = o;
}

__global__ __launch_bounds__(256) void zero_f32_kernel(float* __restrict__ p) {
    int i = blockIdx.x * 256 + threadIdx.x;
    floatx4 z = {0.f, 0.f, 0.f, 0.f};
    ((floatx4*)p)[i] = z;
}

// ---------------- SMALL path GEMM1 (per-expert dispatch) ----------------
__global__ __launch_bounds__(256, 2) void gemm1_kernel(const u16* __restrict__ x,
                                                       const u16* __restrict__ w1e,
                                                       const u16* __restrict__ v1e,
                                                       u16* __restrict__ h12,
                                                       const int* __restrict__ cnt,
                                                       const int* __restrict__ lists,
                                                       int e) {
    const int cnt_e = cnt[e];
    const int m0 = blockIdx.y * 128;
    if (m0 >= cnt_e) return;
    __shared__ __align__(16) u16 lA[128 * 32];
    __shared__ __align__(16) u16 lB1[128 * 32];
    __shared__ __align__(16) u16 lB2[128 * 32];
    const int n0 = blockIdx.x * 128;
    const int w = threadIdx.x >> 6;
    const int lane = threadIdx.x & 63;
    const int wm = w >> 1, wn = w & 1;
    const int srow = lane >> 2;
    const int scol = (lane & 3) * 8;
    const int lrow = lane & 15;
    const int lkq = (lane >> 4) * 8;

    const int* le = lists + e * T_TOK;
    const u16* gA[2];
#pragma unroll
    for (int r = 0; r < 2; ++r) {
        int seg = w * 2 + r;
        int row = seg * 16 + srow;
        gA[r] = x + (size_t)le[m0 + row] * H_DIM + scol;
    }

    floatx4 acc1[4][4], acc2[4][4];
    floatx4 z = {0.f, 0.f, 0.f, 0.f};
#pragma unroll
    for (int mt = 0; mt < 4; ++mt)
#pragma unroll
        for (int nt = 0; nt < 4; ++nt) { acc1[mt][nt] = z; acc2[mt][nt] = z; }

    for (int k0 = 0; k0 < H_DIM; k0 += 32) {
#pragma unroll
        for (int r = 0; r < 2; ++r) {
            int seg = w * 2 + r;
            int row = seg * 16 + srow;
            GLOAD_LDS16(gA[r] + k0, lA + seg * 512);
            GLOAD_LDS16(w1e + (size_t)(n0 + row) * H_DIM + k0 + scol, lB1 + seg * 512);
            GLOAD_LDS16(v1e + (size_t)(n0 + row) * H_DIM + k0 + scol, lB2 + seg * 512);
        }
        __syncthreads();
        bf16x8 a[4], b1[4], b2[4];
#pragma unroll
        for (int mt = 0; mt < 4; ++mt)
            a[mt] = *(const bf16x8*)(lA + (wm * 64 + mt * 16 + lrow) * 32 + lkq);
#pragma unroll
        for (int nt = 0; nt < 4; ++nt) {
            b1[nt] = *(const bf16x8*)(lB1 + (wn * 64 + nt * 16 + lrow) * 32 + lkq);
            b2[nt] = *(const bf16x8*)(lB2 + (wn * 64 + nt * 16 + lrow) * 32 + lkq);
        }
#pragma unroll
        for (int mt = 0; mt < 4; ++mt)
#pragma unroll
            for (int nt = 0; nt < 4; ++nt) {
                acc1[mt][nt] = __builtin_amdgcn_mfma_f32_16x16x32_bf16(a[mt], b1[nt], acc1[mt][nt], 0, 0, 0);
                acc2[mt][nt] = __builtin_amdgcn_mfma_f32_16x16x32_bf16(a[mt], b2[nt], acc2[mt][nt], 0, 0, 0);
            }
        __syncthreads();
    }
    const int orow = (lane >> 4) * 4;
    const int ocol = lane & 15;
#pragma unroll
    for (int mt = 0; mt < 4; ++mt) {
#pragma unroll
        for (int i = 0; i < 4; ++i) {
            int row = m0 + wm * 64 + mt * 16 + orow + i;
            u16* dst = h12 + (size_t)row * F_DIM + n0 + wn * 64;
#pragma unroll
            for (int nt = 0; nt < 4; ++nt) {
                dst[nt * 16 + ocol] = f2bf(gelu_tanh(acc1[mt][nt][i]) * acc2[mt][nt][i]);
            }
        }
    }
}

// ---------------- SMALL path GEMM2 (per-expert dispatch, split-K=4, atomics) ----------------
__global__ __launch_bounds__(256, 2) void gemm2_kernel(const u16* __restrict__ h12,
                                                       const u16* __restrict__ w2te,
                                                       const float* __restrict__ cw,
                                                       float* __restrict__ out_f32,
                                                       const int* __restrict__ cnt,
                                                       const int* __restrict__ lists,
                                                       int e) {
    const int cnt_e = cnt[e];
    const int m0 = blockIdx.y * 128;
    if (m0 >= cnt_e) return;
    __shared__ __align__(16) u16 lA[128 * 32];
    __shared__ __align__(16) u16 lB[128 * 32];
    const int n0 = blockIdx.x * 128;
    const int kz = blockIdx.z * (F_DIM / KSPLIT);
    const int w = threadIdx.x >> 6;
    const int lane = threadIdx.x & 63;
    const int wm = w >> 1, wn = w & 1;
    const int srow = lane >> 2;
    const int scol = (lane & 3) * 8;
    const int lrow = lane & 15;
    const int lkq = (lane >> 4) * 8;

    floatx4 acc[4][4];
    floatx4 z = {0.f, 0.f, 0.f, 0.f};
#pragma unroll
    for (int mt = 0; mt < 4; ++mt)
#pragma unroll
        for (int nt = 0; nt < 4; ++nt) acc[mt][nt] = z;

    for (int k0 = kz; k0 < kz + F_DIM / KSPLIT; k0 += 32) {
#pragma unroll
        for (int r = 0; r < 2; ++r) {
            int seg = w * 2 + r;
            int row = seg * 16 + srow;
            GLOAD_LDS16(h12 + (size_t)(m0 + row) * F_DIM + k0 + scol, lA + seg * 512);
            GLOAD_LDS16(w2te + (size_t)(n0 + row) * F_DIM + k0 + scol, lB + seg * 512);
        }
        __syncthreads();
        bf16x8 a[4], b[4];
#pragma unroll
        for (int mt = 0; mt < 4; ++mt)
            a[mt] = *(const bf16x8*)(lA + (wm * 64 + mt * 16 + lrow) * 32 + lkq);
#pragma unroll
        for (int nt = 0; nt < 4; ++nt)
            b[nt] = *(const bf16x8*)(lB + (wn * 64 + nt * 16 + lrow) * 32 + lkq);
#pragma unroll
        for (int mt = 0; mt < 4; ++mt)
#pragma unroll
            for (int nt = 0; nt < 4; ++nt)
                acc[mt][nt] = __builtin_amdgcn_mfma_f32_16x16x32_bf16(a[mt], b[nt], acc[mt][nt], 0, 0, 0);
        __syncthreads();
    }
    const int orow = (lane >> 4) * 4;
    const int ocol = lane & 15;
    const int* le = lists + e * T_TOK;
#pragma unroll
    for (int mt = 0; mt < 4; ++mt) {
#pragma unroll
        for (int i = 0; i < 4; ++i) {
            int slot = m0 + wm * 64 + mt * 16 + orow + i;
            if (slot >= cnt_e) continue;
            int tok = le[slot];
            float cwv = cw[tok * E_NUM + e];
            float* dst = out_f32 + (size_t)tok * H_DIM + n0 + wn * 64;
#pragma unroll
            for (int nt = 0; nt < 4; ++nt) {
                unsafeAtomicAdd(&dst[nt * 16 + ocol], acc[mt][nt][i] * cwv);
            }
        }
    }
}

// ---------------- BIG path: all experts fused in one dispatch ----------------
// h12 slot space: expert e occupies [base_e, base_e + ceil128(cnt_e)), base from cnt[] prefix.
__device__ __forceinline__ int slot_base(const int* cnt, int e) {
    int base = 0;
    for (int j = 0; j < e; ++j) base += (cnt[j] + 127) & ~127;
    return base;
}

__global__ __launch_bounds__(256, 2) void gemm1_all_kernel(const u16* __restrict__ x,
                                                           const u16* __restrict__ w1all,
                                                           const u16* __restrict__ v1all,
                                                           u16* __restrict__ h12,
                                                           const int* __restrict__ cnt,
                                                           const int* __restrict__ lists) {
    const int e = blockIdx.z;
    const int cnt_e = cnt[e];
    const int m0 = blockIdx.y * 128;
    if (m0 >= cnt_e) return;
    const int base = slot_base(cnt, e);
    const u16* w1e = w1all + (size_t)e * FH;
    const u16* v1e = v1all + (size_t)e * FH;
    __shared__ __align__(16) u16 lA[128 * 32];
    __shared__ __align__(16) u16 lB1[128 * 32];
    __shared__ __align__(16) u16 lB2[128 * 32];
    const int n0 = blockIdx.x * 128;
    const int w = threadIdx.x >> 6;
    const int lane = threadIdx.x & 63;
    const int wm = w >> 1, wn = w & 1;
    const int srow = lane >> 2;
    const int scol = (lane & 3) * 8;
    const int lrow = lane & 15;
    const int lkq = (lane >> 4) * 8;

    const int* le = lists + e * T_TOK;
    const u16* gA[2];
#pragma unroll
    for (int r = 0; r < 2; ++r) {
        int seg = w * 2 + r;
        int row = seg * 16 + srow;
        gA[r] = x + (size_t)le[m0 + row] * H_DIM + scol;
    }

    floatx4 acc1[4][4], acc2[4][4];
    floatx4 z = {0.f, 0.f, 0.f, 0.f};
#pragma unroll
    for (int mt = 0; mt < 4; ++mt)
#pragma unroll
        for (int nt = 0; nt < 4; ++nt) { acc1[mt][nt] = z; acc2[mt][nt] = z; }

    for (int k0 = 0; k0 < H_DIM; k0 += 32) {
#pragma unroll
        for (int r = 0; r < 2; ++r) {
            int seg = w * 2 + r;
            int row = seg * 16 + srow;
            GLOAD_LDS16(gA[r] + k0, lA + seg * 512);
            GLOAD_LDS16(w1e + (size_t)(n0 + row) * H_DIM + k0 + scol, lB1 + seg * 512);
            GLOAD_LDS16(v1e + (size_t)(n0 + row) * H_DIM + k0 + scol, lB2 + seg * 512);
        }
        __syncthreads();
        bf16x8 a[4], b1[4], b2[4];
#pragma unroll
        for (int mt = 0; mt < 4; ++mt)
            a[mt] = *(const bf16x8*)(lA + (wm * 64 + mt * 16 + lrow) * 32 + lkq);
#pragma unroll
        for (int nt = 0; nt < 4; ++nt) {
            b1[nt] = *(const bf16x8*)(lB1 + (wn * 64 + nt * 16 + lrow) * 32 + lkq);
            b2[nt] = *(const bf16x8*)(lB2 + (wn * 64 + nt * 16 + lrow) * 32 + lkq);
        }
#pragma unroll
        for (int mt = 0; mt < 4; ++mt)
#pragma unroll
            for (int nt = 0; nt < 4; ++nt) {
                acc1[mt][nt] = __builtin_amdgcn_mfma_f32_16x16x32_bf16(a[mt], b1[nt], acc1[mt][nt], 0, 0, 0);
                acc2[mt][nt] = __builtin_amdgcn_mfma_f32_16x16x32_bf16(a[mt], b2[nt], acc2[mt][nt], 0, 0, 0);
            }
        __syncthreads();
    }
    const int orow = (lane >> 4) * 4;
    const int ocol = lane & 15;
#pragma unroll
    for (int mt = 0; mt < 4; ++mt) {
#pragma unroll
        for (int i = 0; i < 4; ++i) {
            int row = base + m0 + wm * 64 + mt * 16 + orow + i;
            u16* dst = h12 + (size_t)row * F_DIM + n0 + wn * 64;
#pragma unroll
            for (int nt = 0; nt < 4; ++nt) {
                dst[nt * 16 + ocol] = f2bf(gelu_tanh(acc1[mt][nt][i]) * acc2[mt][nt][i]);
            }
        }
    }
}

__global__ __launch_bounds__(256, 2) void gemm2_all_kernel(const u16* __restrict__ h12,
                                                           const u16* __restrict__ w2tall,
                                                           const float* __restrict__ cw,
                                                           float* __restrict__ out_f32,
                                                           const int* __restrict__ cnt,
                                                           const int* __restrict__ lists) {
    const int e = blockIdx.z >> 1;
    const int ks = blockIdx.z & 1;
    const int cnt_e = cnt[e];
    const int m0 = blockIdx.y * 128;
    if (m0 >= cnt_e) return;
    const int base = slot_base(cnt, e);
    const u16* w2te = w2tall + (size_t)e * FH;
    __shared__ __align__(16) u16 lA[128 * 32];
    __shared__ __align__(16) u16 lB[128 * 32];
    const int n0 = blockIdx.x * 128;
    const int kz = ks * (F_DIM / KSPLIT2);
    const int w = threadIdx.x >> 6;
    const int lane = threadIdx.x & 63;
    const int wm = w >> 1, wn = w & 1;
    const int srow = lane >> 2;
    const int scol = (lane & 3) * 8;
    const int lrow = lane & 15;
    const int lkq = (lane >> 4) * 8;

    floatx4 acc[4][4];
    floatx4 z = {0.f, 0.f, 0.f, 0.f};
#pragma unroll
    for (int mt = 0; mt < 4; ++mt)
#pragma unroll
        for (int nt = 0; nt < 4; ++nt) acc[mt][nt] = z;

    for (int k0 = kz; k0 < kz + F_DIM / KSPLIT2; k0 += 32) {
#pragma unroll
        for (int r = 0; r < 2; ++r) {
            int seg = w * 2 + r;
            int row = seg * 16 + srow;
            GLOAD_LDS16(h12 + (size_t)(base + m0 + row) * F_DIM + k0 + scol, lA + seg * 512);
            GLOAD_LDS16(w2te + (size_t)(n0 + row) * F_DIM + k0 + scol, lB + seg * 512);
        }
        __syncthreads();
        bf16x8 a[4], b[4];
#pragma unroll
        for (int mt = 0; mt < 4; ++mt)
            a[mt] = *(const bf16x8*)(lA + (wm * 64 + mt * 16 + lrow) * 32 + lkq);
#pragma unroll
        for (int nt = 0; nt < 4; ++nt)
            b[nt] = *(const bf16x8*)(lB + (wn * 64 + nt * 16 + lrow) * 32 + lkq);
#pragma unroll
        for (int mt = 0; mt < 4; ++mt)
#pragma unroll
            for (int nt = 0; nt < 4; ++nt)
                acc[mt][nt] = __builtin_amdgcn_mfma_f32_16x16x32_bf16(a[mt], b[nt], acc[mt][nt], 0, 0, 0);
        __syncthreads();
    }
    const int orow = (lane >> 4) * 4;
    const int ocol = lane & 15;
    const int* le = lists + e * T_TOK;
#pragma unroll
    for (int mt = 0; mt < 4; ++mt) {
#pragma unroll
        for (int i = 0; i < 4; ++i) {
            int slot = m0 + wm * 64 + mt * 16 + orow + i;
            if (slot >= cnt_e) continue;
            int tok = le[slot];
            float cwv = cw[tok * E_NUM + e];
            float* dst = out_f32 + (size_t)tok * H_DIM + n0 + wn * 64;
#pragma unroll
            for (int nt = 0; nt < 4; ++nt) {
                unsafeAtomicAdd(&dst[nt * 16 + ocol], acc[mt][nt][i] * cwv);
            }
        }
    }
}

extern "C" void kernel_launch(void* const* d_in, const int* in_sizes, int n_in,
                              void* d_out, int out_size, void* d_ws, size_t ws_size,
                              hipStream_t stream) {
    const float* x = (const float*)d_in[0];
    const float* rw = (const float*)d_in[1];
    const float* w1 = (const float*)d_in[2];
    const float* v1 = (const float*)d_in[3];
    const float* w2 = (const float*)d_in[4];
    float* out = (float*)d_out;

    char* ws = (char*)d_ws;
    // head (both paths): cw 128KB @0, lists 128KB @128KB, cnt 32B @256KB, top2 16KB @0x41000
    float* cw = (float*)ws;
    int* lists = (int*)(ws + 0x20000);
    int* cnt = (int*)(ws + 0x40000);
    int* top2 = (int*)(ws + 0x41000);

    const int n_x = T_TOK * H_DIM;  // 4 M
    const int n_w = FH;             // 4 M per expert
    const size_t MB = 1ull << 20;
    const size_t BIG_NEED = 273 * MB;

    // common prologue
    zero_f32_kernel<<<65, 256, 0, stream>>>((float*)ws);  // zero cw+lists+cnt (266240 B)
    zero_f32_kernel<<<(T_TOK * H_DIM / 4) / 256, 256, 0, stream>>>(out);
    router_kernel<<<T_TOK / 4, 256, 0, stream>>>(x, rw, cw, top2);
    build_lists_kernel<<<E_NUM, 256, 0, stream>>>(top2, cnt, lists);

    if (ws_size >= BIG_NEED) {
        // BIG layout: xb @1MB (8MB), h12 @9MB (72MB), w1b @81MB (64MB), v1b @145MB (64MB), w2tb @209MB (64MB)
        u16* xb = (u16*)(ws + 1 * MB);
        u16* h12 = (u16*)(ws + 9 * MB);
        u16* w1b = (u16*)(ws + 81 * MB);
        u16* v1b = (u16*)(ws + 145 * MB);
        u16* w2tb = (u16*)(ws + 209 * MB);

        convert_bf16_kernel<<<(n_x / 4) / 256, 256, 0, stream>>>(x, xb, n_x);
        convert2_bf16_kernel<<<(2 * E_NUM * n_w / 4) / 256, 256, 0, stream>>>(w1, w1b, v1, v1b, E_NUM * n_w);
        transpose_convert_w2<<<dim3(F_DIM / 32, H_DIM / 32, E_NUM), 256, 0, stream>>>(w2, w2tb);
        gemm1_all_kernel<<<dim3(F_DIM / 128, T_TOK / 128, E_NUM), 256, 0, stream>>>(xb, w1b, v1b, h12, cnt, lists);
        gemm2_all_kernel<<<dim3(H_DIM / 128, T_TOK / 128, E_NUM * KSPLIT2), 256, 0, stream>>>(h12, w2tb, cw, out, cnt, lists);
    } else {
        // SMALL layout (verified): h12 @1MB (32MB), xb @33MB, w1b @41MB, v1b @49MB, w2tb @57MB
        u16* h12 = (u16*)(ws + (1u << 20));
        u16* xb = (u16*)(ws + (33u << 20));
        u16* w1b = (u16*)(ws + (41u << 20));
        u16* v1b = (u16*)(ws + (49u << 20));
        u16* w2tb = (u16*)(ws + (57u << 20));

        convert_bf16_kernel<<<(n_x / 4) / 256, 256, 0, stream>>>(x, xb, n_x);
        for (int e = 0; e < E_NUM; ++e) {
            const float* w1e = w1 + (size_t)e * n_w;
            const float* v1e = v1 + (size_t)e * n_w;
            const float* w2e = w2 + (size_t)e * n_w;
            convert2_bf16_kernel<<<(2 * n_w / 4) / 256, 256, 0, stream>>>(w1e, w1b, v1e, v1b, n_w);
            transpose_convert_w2<<<dim3(F_DIM / 32, H_DIM / 32, 1), 256, 0, stream>>>(w2e, w2tb);
            gemm1_kernel<<<dim3(F_DIM / 128, T_TOK / 128), 256, 0, stream>>>(xb, w1b, v1b, h12, cnt, lists, e);
            gemm2_kernel<<<dim3(H_DIM / 128, T_TOK / 128, KSPLIT), 256, 0, stream>>>(h12, w2tb, cw, out, cnt, lists, e);
        }
    }
}